// Round 7
// baseline (129.352 us; speedup 1.0000x reference)
//
#include <hip/hip_runtime.h>

// Problem constants: B=16, C=512, H=W=14 (HW=196), D=8000.
#define B_DIM 16
#define C_DIM 512
#define HW_DIM 196
#define D_DIM 8000
#define KP 224                      // K padded to 7*32 for MFMA 16x16x32
#define NROW (B_DIM * C_DIM)        // 8192 rows in xp

typedef __attribute__((ext_vector_type(8))) short short8;   // 8 bf16 frag
typedef __attribute__((ext_vector_type(4))) float float4v;  // 4 f32 acc

// ---------------------------------------------------------------------------
// Kernel 1 (prep), 1024 blocks:
//  blocks 0..511:   extract (hash,sign) of 2 rows of S1|S2 with chunked
//                   early-exit scan (~55% of bytes read on average).
//  blocks 512..1023: convert 16 rows of x fp32 -> bf16, pad K 196 -> 224.
//  block 512 also zeroes the per-batch completion counters.
// ---------------------------------------------------------------------------
__global__ __launch_bounds__(256) void prep(
    const float* __restrict__ x, const float* __restrict__ S1,
    const float* __restrict__ S2,
    int* __restrict__ h, float* __restrict__ s,
    unsigned short* __restrict__ xp, unsigned int* __restrict__ cnt) {
    const int bid = blockIdx.x;
    const int tid = threadIdx.x;
    if (bid < 2 * C_DIM / 2) {
        __shared__ int found;
        for (int rr = 0; rr < 2; ++rr) {
            const int r     = bid * 2 + rr;
            const int row   = r & (C_DIM - 1);
            const int which = r >> 9;
            const float4* rowp = (const float4*)((which ? S2 : S1) + (size_t)row * D_DIM);
            int*   hp = h + which * C_DIM;
            float* sp = s + which * C_DIM;
            if (tid == 0) found = 0;
            __syncthreads();
            for (int c = 0; c < 8; ++c) {            // 8 chunks of 256 float4
                int j4 = c * 256 + tid;
                if (j4 < D_DIM / 4) {
                    float4 v = rowp[j4];
                    if (v.x != 0.f) { hp[row] = 4 * j4 + 0; sp[row] = v.x; found = 1; }
                    if (v.y != 0.f) { hp[row] = 4 * j4 + 1; sp[row] = v.y; found = 1; }
                    if (v.z != 0.f) { hp[row] = 4 * j4 + 2; sp[row] = v.z; found = 1; }
                    if (v.w != 0.f) { hp[row] = 4 * j4 + 3; sp[row] = v.w; found = 1; }
                }
                __syncthreads();
                if (found) break;                    // uniform after barrier
            }
            __syncthreads();                         // order vs next reset
        }
    } else {
        const int j = bid - 512;                     // 0..511, 16 rows each
        if (j == 0 && tid < B_DIM) cnt[tid] = 0;     // zero completion counters
        #pragma unroll
        for (int l = 0; l < 14; ++l) {               // 14*256 = 3584 = 16*224
            int idx = l * 256 + tid;
            int r   = idx / KP;
            int kk  = idx - r * KP;
            int row = j * 16 + r;
            float v = (kk < HW_DIM) ? x[(size_t)row * HW_DIM + kk] : 0.0f;
            unsigned int u = __float_as_uint(v);     // RNE fp32 -> bf16
            u = (u + 0x7FFFu + ((u >> 16) & 1u)) >> 16;
            xp[(size_t)row * KP + kk] = (unsigned short)u;
        }
    }
}

// ---------------------------------------------------------------------------
// Kernel 2: barrier-free MFMA Gram (128x128 block tile) + LDS-histogram
// scatter + coalesced float4 flush to a per-block partial + last-block-done
// reduction of the 16 partials per batch (atomic counter; no grid sync).
// Grid: (4 j, 4 i, 16 b) = 256 blocks. LDS = 32 KB histogram only.
// ---------------------------------------------------------------------------
__global__ __launch_bounds__(256, 1) void gram_hist(
    const unsigned short* __restrict__ xp,   // [B*C, KP] bf16 bits
    const int* __restrict__ h, const float* __restrict__ s,
    float* __restrict__ part,                // [256, D] partials
    unsigned int* __restrict__ cnt,          // [16] completion counters
    float* __restrict__ out) {               // [B, D]
    const int jb = blockIdx.x;
    const int ib = blockIdx.y;
    const int b  = blockIdx.z;
    const int i0 = ib * 128;
    const int j0 = jb * 128;
    const int tid = threadIdx.x;

    __shared__ __align__(16) float hist[D_DIM];
    __shared__ int lastFlag;

    #pragma unroll
    for (int l4 = 0; l4 < 7; ++l4)                   // 7*256 = 1792
        ((float4*)hist)[l4 * 256 + tid] = (float4){0.f, 0.f, 0.f, 0.f};
    if (tid < 2000 - 1792)
        ((float4*)hist)[1792 + tid] = (float4){0.f, 0.f, 0.f, 0.f};
    __syncthreads();

    const int w  = tid >> 6;    // wave 0..3 -> i rows [i0+32w, +32)
    const int l  = tid & 63;
    const int rA = l & 15;      // fragment row within 16x16 tile
    const int g  = l >> 4;      // k-group: 8 contiguous k at g*8

    const unsigned short* base = xp + (size_t)b * C_DIM * KP;
    const unsigned short* pA[2];
    const unsigned short* pB[8];
    #pragma unroll
    for (int mt = 0; mt < 2; ++mt)
        pA[mt] = base + (size_t)(i0 + w * 32 + mt * 16 + rA) * KP + g * 8;
    #pragma unroll
    for (int nt = 0; nt < 8; ++nt)
        pB[nt] = base + (size_t)(j0 + nt * 16 + rA) * KP + g * 8;

    float4v acc[2][8];
    #pragma unroll
    for (int mt = 0; mt < 2; ++mt)
        #pragma unroll
        for (int nt = 0; nt < 8; ++nt)
            acc[mt][nt] = (float4v){0.0f, 0.0f, 0.0f, 0.0f};

    short8 fa[2], fb[8];
    #pragma unroll
    for (int mt = 0; mt < 2; ++mt) fa[mt] = *(const short8*)pA[mt];
    #pragma unroll
    for (int nt = 0; nt < 8; ++nt) fb[nt] = *(const short8*)pB[nt];

    // 7 K-steps of 32; register double-buffered prefetch; zero barriers.
    #pragma unroll
    for (int step = 1; step <= 7; ++step) {
        short8 na[2], nb[8];
        if (step < 7) {
            #pragma unroll
            for (int mt = 0; mt < 2; ++mt) na[mt] = *(const short8*)(pA[mt] + step * 32);
            #pragma unroll
            for (int nt = 0; nt < 8; ++nt) nb[nt] = *(const short8*)(pB[nt] + step * 32);
        }
        #pragma unroll
        for (int mt = 0; mt < 2; ++mt)
            #pragma unroll
            for (int nt = 0; nt < 8; ++nt)
                acc[mt][nt] = __builtin_amdgcn_mfma_f32_16x16x32_bf16(
                    fa[mt], fb[nt], acc[mt][nt], 0, 0, 0);
        if (step < 7) {
            #pragma unroll
            for (int mt = 0; mt < 2; ++mt) fa[mt] = na[mt];
            #pragma unroll
            for (int nt = 0; nt < 8; ++nt) fb[nt] = nb[nt];
        }
    }

    // Scatter: C/D layout col = lane&15, row = (lane>>4)*4 + reg (verified).
    int hr[2][4]; float sr[2][4]; int hc[8]; float sc[8];
    #pragma unroll
    for (int mt = 0; mt < 2; ++mt)
        #pragma unroll
        for (int rg = 0; rg < 4; ++rg) {
            int c1 = i0 + w * 32 + mt * 16 + (l >> 4) * 4 + rg;
            hr[mt][rg] = h[c1]; sr[mt][rg] = s[c1];
        }
    #pragma unroll
    for (int nt = 0; nt < 8; ++nt) {
        int c2 = j0 + nt * 16 + (l & 15);
        hc[nt] = h[C_DIM + c2]; sc[nt] = s[C_DIM + c2];
    }
    #pragma unroll
    for (int mt = 0; mt < 2; ++mt)
        #pragma unroll
        for (int nt = 0; nt < 8; ++nt)
            #pragma unroll
            for (int rg = 0; rg < 4; ++rg) {
                int bin = hr[mt][rg] + hc[nt];
                if (bin >= D_DIM) bin -= D_DIM;
                atomicAdd(&hist[bin], sr[mt][rg] * sc[nt] * acc[mt][nt][rg]);
            }
    __syncthreads();

    // Flush: plain coalesced float4 stores to this block's partial slice.
    const int slot = (b * 4 + ib) * 4 + jb;          // b*16 + ib*4 + jb
    float* pb = part + (size_t)slot * D_DIM;
    #pragma unroll
    for (int l4 = 0; l4 < 7; ++l4)
        ((float4*)pb)[l4 * 256 + tid] = ((const float4*)hist)[l4 * 256 + tid];
    if (tid < 2000 - 1792)
        ((float4*)pb)[1792 + tid] = ((const float4*)hist)[1792 + tid];
    __syncthreads();                                 // all stores issued

    // Last-block-done: the 16th finisher of batch b reduces its partials.
    if (tid == 0) {
        __threadfence();                             // publish flush stores
        unsigned int old = atomicAdd(&cnt[b], 1u);   // device-scope
        lastFlag = (old == 15u);
    }
    __syncthreads();
    if (lastFlag) {
        __threadfence();                             // acquire others' stores
        const float4* pp = (const float4*)(part + (size_t)b * 16 * D_DIM);
        float4* ob = (float4*)(out + (size_t)b * D_DIM);
        for (int i4 = tid; i4 < D_DIM / 4; i4 += 256) {
            float4 v = {0.f, 0.f, 0.f, 0.f};
            #pragma unroll
            for (int t = 0; t < 16; ++t) {
                float4 p = pp[(size_t)t * (D_DIM / 4) + i4];
                v.x += p.x; v.y += p.y; v.z += p.z; v.w += p.w;
            }
            ob[i4] = v;
        }
    }
}

extern "C" void kernel_launch(void* const* d_in, const int* in_sizes, int n_in,
                              void* d_out, int out_size, void* d_ws, size_t ws_size,
                              hipStream_t stream) {
    const float* x  = (const float*)d_in[0];  // [16, 512, 14, 14] fp32
    const float* S1 = (const float*)d_in[1];  // [512, 8000] fp32
    const float* S2 = (const float*)d_in[2];  // [512, 8000] fp32
    float* out = (float*)d_out;               // [16, 8000] fp32

    // ws: h[1024] int | s[1024] f32 | xp[8192*224] bf16 (3.7 MB)
    //   | part[256*8000] f32 (8.2 MB) | cnt[16] u32
    int*            h    = (int*)d_ws;
    float*          s    = (float*)(h + 2 * C_DIM);
    unsigned short* xp   = (unsigned short*)(s + 2 * C_DIM);
    float*          part = (float*)(xp + (size_t)NROW * KP);
    unsigned int*   cnt  = (unsigned int*)(part + 256 * D_DIM);

    prep<<<1024, 256, 0, stream>>>(x, S1, S2, h, s, xp, cnt);

    dim3 grid(4, 4, B_DIM);                   // 256 blocks, 128x128 tiles
    gram_hist<<<grid, 256, 0, stream>>>(xp, h, s, part, cnt, out);
}